// Round 1
// baseline (911.943 us; speedup 1.0000x reference)
//
#include <hip/hip_runtime.h>
#include <math.h>

#define TOKENS 16384
#define DIM    4096
#define NEXP   64
#define KSPLIT 8
#define KSLICE (DIM / KSPLIT)   // 512
#define BK     32
#define NCHUNK (KSLICE / BK)    // 16
#define XS_STRIDE 36            // pad 32->36 floats: float4-aligned, breaks 32-bank stride

// ---------------- Kernel 1: split-K router GEMM ----------------
// grid (64, 8), block 256. Each thread owns one token, 64 fp32 accumulators.
// W rows are read via wave-uniform addresses -> scalar (SMEM) loads, broadcast
// free across lanes. x staged through LDS with coalesced float4 global loads,
// software-pipelined one chunk ahead.
__global__ __launch_bounds__(256, 2)
void router_gemm_kernel(const float* __restrict__ x,
                        const float* __restrict__ w,
                        float* __restrict__ part) {
    __shared__ float xs[256 * XS_STRIDE];
    const int tid = threadIdx.x;
    const int tb  = blockIdx.x;   // token block 0..63
    const int ks  = blockIdx.y;   // K-split 0..7
    const int token0 = tb * 256;
    const int k0     = ks * KSLICE;

    // staging map: flat f4-index = tid + 256*j  ->  row = idx/8, c4 = idx%8
    const int srow = tid >> 3;    // base row; +32 per j
    const int sc4  = tid & 7;

    float acc[NEXP];
#pragma unroll
    for (int e = 0; e < NEXP; ++e) acc[e] = 0.f;

    // prefetch chunk 0 into registers
    float4 pre[8];
    {
        const float* gp = x + (size_t)token0 * DIM + k0;
#pragma unroll
        for (int j = 0; j < 8; ++j) {
            const int row = srow + 32 * j;
            pre[j] = *(const float4*)(gp + (size_t)row * DIM + (sc4 << 2));
        }
    }

    for (int c = 0; c < NCHUNK; ++c) {
        __syncthreads();   // xs free from previous chunk's compute
#pragma unroll
        for (int j = 0; j < 8; ++j) {
            const int row = srow + 32 * j;
            *(float4*)&xs[row * XS_STRIDE + (sc4 << 2)] = pre[j];
        }
        __syncthreads();

        // prefetch next chunk while computing this one
        if (c + 1 < NCHUNK) {
            const float* gp = x + (size_t)token0 * DIM + k0 + (c + 1) * BK;
#pragma unroll
            for (int j = 0; j < 8; ++j) {
                const int row = srow + 32 * j;
                pre[j] = *(const float4*)(gp + (size_t)row * DIM + (sc4 << 2));
            }
        }

        // my token's x chunk -> registers (reused across all 64 experts)
        float xr[BK];
#pragma unroll
        for (int j = 0; j < 8; ++j) {
            const float4 v = *(const float4*)&xs[tid * XS_STRIDE + (j << 2)];
            xr[4 * j + 0] = v.x; xr[4 * j + 1] = v.y;
            xr[4 * j + 2] = v.z; xr[4 * j + 3] = v.w;
        }

        // expert loop: W addresses are wave-uniform -> scalar loads
        const float* wp = w + k0 + c * BK;
#pragma unroll
        for (int e = 0; e < NEXP; ++e) {
            const float* we = wp + (size_t)e * DIM;
            float s0 = 0.f;
#pragma unroll
            for (int kk = 0; kk < BK; ++kk)
                s0 = fmaf(we[kk], xr[kk], s0);
            acc[e] += s0;
        }
    }

    // partials: part[ks][token][e], float4 stores
    float* pout = part + ((size_t)ks * TOKENS + token0 + tid) * NEXP;
#pragma unroll
    for (int e4 = 0; e4 < NEXP / 4; ++e4) {
        float4 v;
        v.x = acc[4 * e4 + 0]; v.y = acc[4 * e4 + 1];
        v.z = acc[4 * e4 + 2]; v.w = acc[4 * e4 + 3];
        *(float4*)(pout + 4 * e4) = v;
    }
}

// ---------------- Kernel 2: split-K reduce + top-2 + softmax ----------------
// One wave per token; lane == expert. Butterfly argmax twice (tiebreak: lower
// index), softmax over the kept 2 logits. Indices written as float values
// (harness reads d_out via the float32 path).
__global__ __launch_bounds__(256)
void topk_kernel(const float* __restrict__ part, float* __restrict__ out) {
    const int lane  = threadIdx.x & 63;
    const int wv    = threadIdx.x >> 6;
    const int token = blockIdx.x * 4 + wv;

    float logit = 0.f;
#pragma unroll
    for (int s = 0; s < KSPLIT; ++s)
        logit += part[((size_t)s * TOKENS + token) * NEXP + lane];

    // top-1
    float v1 = logit; int i1 = lane;
#pragma unroll
    for (int off = 32; off > 0; off >>= 1) {
        const float ov = __shfl_xor(v1, off);
        const int   oi = __shfl_xor(i1, off);
        if (ov > v1 || (ov == v1 && oi < i1)) { v1 = ov; i1 = oi; }
    }
    // top-2: mask the winner
    float v2 = (lane == i1) ? -INFINITY : logit; int i2 = lane;
#pragma unroll
    for (int off = 32; off > 0; off >>= 1) {
        const float ov = __shfl_xor(v2, off);
        const int   oi = __shfl_xor(i2, off);
        if (ov > v2 || (ov == v2 && oi < i2)) { v2 = ov; i2 = oi; }
    }

    if (lane == 0) {
        const float e = expf(v2 - v1);       // <= 1, no overflow
        const float r = 1.f / (1.f + e);
        out[2 * token + 0] = r;              // score of top-1
        out[2 * token + 1] = e * r;          // score of top-2
        out[2 * TOKENS + 2 * token + 0] = (float)i1;
        out[2 * TOKENS + 2 * token + 1] = (float)i2;
    }
}

extern "C" void kernel_launch(void* const* d_in, const int* in_sizes, int n_in,
                              void* d_out, int out_size, void* d_ws, size_t ws_size,
                              hipStream_t stream) {
    const float* x = (const float*)d_in[0];   // (4,4096,4096) fp32
    const float* w = (const float*)d_in[1];   // (64,4096) fp32
    float* out  = (float*)d_out;              // 32768 scores + 32768 float-encoded indices
    float* part = (float*)d_ws;               // KSPLIT*TOKENS*NEXP*4 = 33.5 MB

    dim3 g1(TOKENS / 256, KSPLIT);
    router_gemm_kernel<<<g1, 256, 0, stream>>>(x, w, part);
    topk_kernel<<<TOKENS / 4, 256, 0, stream>>>(part, out);
}

// Round 2
// 589.849 us; speedup vs baseline: 1.5461x; 1.5461x over previous
//
#include <hip/hip_runtime.h>
#include <math.h>

#define TOKENS 16384
#define DIM    4096
#define NEXP   64
#define KSPLIT 4
#define KSLICE (DIM / KSPLIT)   // 1024
#define BK     32
#define NCHUNK (KSLICE / BK)    // 32
#define TB     64               // tokens per block
#define EPT    16               // experts per thread (one expert-group per wave)
#define XS_STRIDE 36            // 36 floats = 144 B: 16B-aligned, spreads bank quads

// ---------------- Kernel 1: split-K router GEMM ----------------
// grid (256, 4), block 256 (4 waves). Wave wv owns experts [16*wv, 16*wv+16)
// for all 64 tokens of the block; thread = (token=lane, 16 experts), acc[16].
// W rows: wave-uniform addresses (egroup forced uniform via readfirstlane) ->
// scalar s_load broadcast. x staged through LDS, prefetched 1 chunk ahead.
__global__ __launch_bounds__(256, 4)
void router_gemm_kernel(const float* __restrict__ x,
                        const float* __restrict__ w,
                        float* __restrict__ part) {
    __shared__ float xs[TB * XS_STRIDE];
    const int tid    = threadIdx.x;
    const int lane   = tid & 63;                                   // token within block
    const int egroup = __builtin_amdgcn_readfirstlane(tid >> 6);   // 0..3, wave-uniform
    const int token0 = blockIdx.x * TB;
    const int k0     = blockIdx.y * KSLICE;
    const int e0     = egroup * EPT;

    // staging map: 64 tokens x 32 k = 512 float4; thread covers f4-slots tid, tid+256
    const int srow = tid >> 3;   // 0..31 (and +32 for the second slot)
    const int sc4  = tid & 7;    // float4 column 0..7

    float acc[EPT];
#pragma unroll
    for (int e = 0; e < EPT; ++e) acc[e] = 0.f;

    // prefetch chunk 0
    float4 pre0, pre1;
    {
        const float* gp = x + (size_t)token0 * DIM + k0 + (sc4 << 2);
        pre0 = *(const float4*)(gp + (size_t)srow * DIM);
        pre1 = *(const float4*)(gp + (size_t)(srow + 32) * DIM);
    }

    for (int c = 0; c < NCHUNK; ++c) {
        __syncthreads();   // previous chunk's xs reads complete
        *(float4*)&xs[srow        * XS_STRIDE + (sc4 << 2)] = pre0;
        *(float4*)&xs[(srow + 32) * XS_STRIDE + (sc4 << 2)] = pre1;
        __syncthreads();

        if (c + 1 < NCHUNK) {
            const float* gp = x + (size_t)token0 * DIM + k0 + (c + 1) * BK + (sc4 << 2);
            pre0 = *(const float4*)(gp + (size_t)srow * DIM);
            pre1 = *(const float4*)(gp + (size_t)(srow + 32) * DIM);
        }

        // my token's 32 x-values -> registers (each feeds 16 FMAs)
        float xr[BK];
#pragma unroll
        for (int j = 0; j < 8; ++j) {
            const float4 v = *(const float4*)&xs[lane * XS_STRIDE + (j << 2)];
            xr[4 * j + 0] = v.x; xr[4 * j + 1] = v.y;
            xr[4 * j + 2] = v.z; xr[4 * j + 3] = v.w;
        }

        // 16 experts x 32 k = 512 FMA; W via wave-uniform scalar loads
        const float* wp = w + k0 + c * BK;
#pragma unroll
        for (int e = 0; e < EPT; ++e) {
            const float* we = wp + (size_t)(e0 + e) * DIM;
            float s = 0.f;
#pragma unroll
            for (int kk = 0; kk < BK; ++kk)
                s = fmaf(we[kk], xr[kk], s);
            acc[e] += s;
        }
    }

    // partials: part[ks][token][e0..e0+15]
    float* pout = part + ((size_t)blockIdx.y * TOKENS + token0 + lane) * NEXP + e0;
#pragma unroll
    for (int e4 = 0; e4 < EPT / 4; ++e4) {
        float4 v;
        v.x = acc[4 * e4 + 0]; v.y = acc[4 * e4 + 1];
        v.z = acc[4 * e4 + 2]; v.w = acc[4 * e4 + 3];
        *(float4*)(pout + 4 * e4) = v;
    }
}

// ---------------- Kernel 2: split-K reduce + top-2 + softmax ----------------
// One wave per token; lane == expert. Butterfly argmax twice (tiebreak: lower
// index). Indices written as float (harness reads d_out via the fp32 path).
__global__ __launch_bounds__(256)
void topk_kernel(const float* __restrict__ part, float* __restrict__ out) {
    const int lane  = threadIdx.x & 63;
    const int wv    = threadIdx.x >> 6;
    const int token = blockIdx.x * 4 + wv;

    float logit = 0.f;
#pragma unroll
    for (int s = 0; s < KSPLIT; ++s)
        logit += part[((size_t)s * TOKENS + token) * NEXP + lane];

    // top-1
    float v1 = logit; int i1 = lane;
#pragma unroll
    for (int off = 32; off > 0; off >>= 1) {
        const float ov = __shfl_xor(v1, off);
        const int   oi = __shfl_xor(i1, off);
        if (ov > v1 || (ov == v1 && oi < i1)) { v1 = ov; i1 = oi; }
    }
    // top-2: mask the winner
    float v2 = (lane == i1) ? -INFINITY : logit; int i2 = lane;
#pragma unroll
    for (int off = 32; off > 0; off >>= 1) {
        const float ov = __shfl_xor(v2, off);
        const int   oi = __shfl_xor(i2, off);
        if (ov > v2 || (ov == v2 && oi < i2)) { v2 = ov; i2 = oi; }
    }

    if (lane == 0) {
        const float e = expf(v2 - v1);       // <= 1, no overflow
        const float r = 1.f / (1.f + e);
        out[2 * token + 0] = r;              // score of top-1
        out[2 * token + 1] = e * r;          // score of top-2
        out[2 * TOKENS + 2 * token + 0] = (float)i1;
        out[2 * TOKENS + 2 * token + 1] = (float)i2;
    }
}

extern "C" void kernel_launch(void* const* d_in, const int* in_sizes, int n_in,
                              void* d_out, int out_size, void* d_ws, size_t ws_size,
                              hipStream_t stream) {
    const float* x = (const float*)d_in[0];   // (4,4096,4096) fp32
    const float* w = (const float*)d_in[1];   // (64,4096) fp32
    float* out  = (float*)d_out;              // 32768 scores + 32768 float-encoded indices
    float* part = (float*)d_ws;               // KSPLIT*TOKENS*NEXP*4 = 16.8 MB

    dim3 g1(TOKENS / TB, KSPLIT);
    router_gemm_kernel<<<g1, 256, 0, stream>>>(x, w, part);
    topk_kernel<<<TOKENS / 4, 256, 0, stream>>>(part, out);
}

// Round 3
// 558.955 us; speedup vs baseline: 1.6315x; 1.0553x over previous
//
#include <hip/hip_runtime.h>
#include <math.h>

#define TOKENS 16384
#define DIM    4096
#define NEXP   64
#define KSPLIT 4
#define KSLICE (DIM / KSPLIT)   // 1024
#define BK     32
#define NCHUNK (KSLICE / BK)    // 32
#define TB     64               // tokens per block
#define EPT    16               // experts per thread (one expert-group per wave)
#define XS_STRIDE 36            // 36 floats: 16B-aligned, spreads bank quads

// ---------------- Kernel 1: split-K router GEMM ----------------
// grid 1024 (swizzled: ks = bid&3 so co-resident blocks share one W k-slice
// in the scalar cache), block 256 (4 waves). Wave wv owns experts
// [16*wv,16*wv+16) for the block's 64 tokens; thread = (token=lane, acc[16]).
// W via wave-uniform scalar loads; x staged through LDS, prefetched 1 chunk
// ahead. amdgpu_waves_per_eu(4,4): pin occupancy target to the grid-limited
// 4 waves/EU -> VGPR budget 128 -> compiler keeps xr[32] RESIDENT instead of
// re-reading LDS per expert (R1: VGPR=40, 136 ds_read_b128/wave/chunk ->
// LDS-pipe bound at ~347us model ~ 331us measured).
__global__ __launch_bounds__(256)
__attribute__((amdgpu_waves_per_eu(4, 4)))
void router_gemm_kernel(const float* __restrict__ x,
                        const float* __restrict__ w,
                        float* __restrict__ part) {
    __shared__ float xs[TB * XS_STRIDE];
    const int tid    = threadIdx.x;
    const int lane   = tid & 63;                                   // token within block
    const int egroup = __builtin_amdgcn_readfirstlane(tid >> 6);   // 0..3, wave-uniform
    const int bid    = blockIdx.x;
    const int ks     = bid & (KSPLIT - 1);   // resident blocks (bid += 256) share ks
    const int tb     = bid >> 2;
    const int token0 = tb * TB;
    const int k0     = ks * KSLICE;
    const int e0     = egroup * EPT;

    // staging map: 64 tokens x 32 k = 512 float4; thread covers f4-slots tid, tid+256
    const int srow = tid >> 3;   // 0..31 (and +32 for the second slot)
    const int sc4  = tid & 7;    // float4 column 0..7

    float acc[EPT];
#pragma unroll
    for (int e = 0; e < EPT; ++e) acc[e] = 0.f;

    // prefetch chunk 0
    float4 pre0, pre1;
    {
        const float* gp = x + (size_t)token0 * DIM + k0 + (sc4 << 2);
        pre0 = *(const float4*)(gp + (size_t)srow * DIM);
        pre1 = *(const float4*)(gp + (size_t)(srow + 32) * DIM);
    }

    for (int c = 0; c < NCHUNK; ++c) {
        __syncthreads();   // previous chunk's xs reads complete
        *(float4*)&xs[srow        * XS_STRIDE + (sc4 << 2)] = pre0;
        *(float4*)&xs[(srow + 32) * XS_STRIDE + (sc4 << 2)] = pre1;
        __syncthreads();

        if (c + 1 < NCHUNK) {
            const float* gp = x + (size_t)token0 * DIM + k0 + (c + 1) * BK + (sc4 << 2);
            pre0 = *(const float4*)(gp + (size_t)srow * DIM);
            pre1 = *(const float4*)(gp + (size_t)(srow + 32) * DIM);
        }

        // my token's 32 x-values -> 8 float4 in VGPRs (feed 16 experts each)
        float4 xr4[8];
#pragma unroll
        for (int j = 0; j < 8; ++j)
            xr4[j] = *(const float4*)&xs[lane * XS_STRIDE + (j << 2)];

        // 16 experts x 32 k = 512 FMA; W via wave-uniform scalar loads.
        // Two independent FMA chains per expert: 16-deep chain @4cyc latency
        // fits the 64-cyc issue window (one 32-chain would stall 2x).
        const float* wp = w + k0 + c * BK;
#pragma unroll
        for (int e = 0; e < EPT; ++e) {
            const float* we = wp + (size_t)(e0 + e) * DIM;
            float s0 = 0.f, s1 = 0.f;
#pragma unroll
            for (int j = 0; j < 8; ++j) {
                const float4 xv = xr4[j];
                s0 = fmaf(we[4 * j + 0], xv.x, s0);
                s1 = fmaf(we[4 * j + 1], xv.y, s1);
                s0 = fmaf(we[4 * j + 2], xv.z, s0);
                s1 = fmaf(we[4 * j + 3], xv.w, s1);
            }
            acc[e] += s0 + s1;
        }
    }

    // partials: part[ks][token][e0..e0+15]
    float* pout = part + ((size_t)ks * TOKENS + token0 + lane) * NEXP + e0;
#pragma unroll
    for (int e4 = 0; e4 < EPT / 4; ++e4) {
        float4 v;
        v.x = acc[4 * e4 + 0]; v.y = acc[4 * e4 + 1];
        v.z = acc[4 * e4 + 2]; v.w = acc[4 * e4 + 3];
        *(float4*)(pout + 4 * e4) = v;
    }
}

// ---------------- Kernel 2: split-K reduce + top-2 + softmax ----------------
// One wave per token; lane == expert. Butterfly argmax twice (tiebreak: lower
// index). Indices written as float (harness reads d_out via the fp32 path).
__global__ __launch_bounds__(256)
void topk_kernel(const float* __restrict__ part, float* __restrict__ out) {
    const int lane  = threadIdx.x & 63;
    const int wv    = threadIdx.x >> 6;
    const int token = blockIdx.x * 4 + wv;

    float logit = 0.f;
#pragma unroll
    for (int s = 0; s < KSPLIT; ++s)
        logit += part[((size_t)s * TOKENS + token) * NEXP + lane];

    // top-1
    float v1 = logit; int i1 = lane;
#pragma unroll
    for (int off = 32; off > 0; off >>= 1) {
        const float ov = __shfl_xor(v1, off);
        const int   oi = __shfl_xor(i1, off);
        if (ov > v1 || (ov == v1 && oi < i1)) { v1 = ov; i1 = oi; }
    }
    // top-2: mask the winner
    float v2 = (lane == i1) ? -INFINITY : logit; int i2 = lane;
#pragma unroll
    for (int off = 32; off > 0; off >>= 1) {
        const float ov = __shfl_xor(v2, off);
        const int   oi = __shfl_xor(i2, off);
        if (ov > v2 || (ov == v2 && oi < i2)) { v2 = ov; i2 = oi; }
    }

    if (lane == 0) {
        const float e = expf(v2 - v1);       // <= 1, no overflow
        const float r = 1.f / (1.f + e);
        out[2 * token + 0] = r;              // score of top-1
        out[2 * token + 1] = e * r;          // score of top-2
        out[2 * TOKENS + 2 * token + 0] = (float)i1;
        out[2 * TOKENS + 2 * token + 1] = (float)i2;
    }
}

extern "C" void kernel_launch(void* const* d_in, const int* in_sizes, int n_in,
                              void* d_out, int out_size, void* d_ws, size_t ws_size,
                              hipStream_t stream) {
    const float* x = (const float*)d_in[0];   // (4,4096,4096) fp32
    const float* w = (const float*)d_in[1];   // (64,4096) fp32
    float* out  = (float*)d_out;              // 32768 scores + 32768 float-encoded indices
    float* part = (float*)d_ws;               // KSPLIT*TOKENS*NEXP*4 = 16.8 MB

    router_gemm_kernel<<<(TOKENS / TB) * KSPLIT, 256, 0, stream>>>(x, w, part);
    topk_kernel<<<TOKENS / 4, 256, 0, stream>>>(part, out);
}